// Round 3
// baseline (232.064 us; speedup 1.0000x reference)
//
#include <hip/hip_runtime.h>

// WavUnPacking: x (8,256,128,128) f32 -> out (8,64,256,256) f32
// Channel quadrants (ll,lh,hl,hh), Haar inverse butterfly into 2x2 blocks.
//
// R2 layout: grid-stride over batch dim, fully unrolled x8 (fill-kernel regime:
// saturate HBM via per-wave ILP, not TLP — the 6.6 TB/s fill runs at 9.7% occ).
// Per thread-iteration:
//   loads : 4 x float2 (ll,lh,hl,hh), 8 B/lane  -> 512 B contiguous per wave instr
//   stores: 2 x float4 NT (rows 2h, 2h+1), 16 B/lane -> 1 KB contiguous per instr
// Batch stride is 16 MB on BOTH input and output -> one pointer add per stream.

typedef float v2f __attribute__((ext_vector_type(2)));
typedef float v4f __attribute__((ext_vector_type(4)));

__global__ __launch_bounds__(256) void wav_unpack_kernel(
    const float* __restrict__ x, float* __restrict__ out) {
    constexpr int H = 128, W = 128;
    constexpr int Q = 64 * H * W;           // quadrant stride  = 1,048,576 elems
    constexpr int BSTRIDE = 256 * H * W;    // batch stride (in AND out) = 4,194,304

    // tid in [0, 2^19): bits 0-5 w2, 6-12 h, 13-18 c (quadrant-local channel)
    int tid = blockIdx.x * blockDim.x + threadIdx.x;
    int w2 = tid & 63;
    int h  = (tid >> 6) & 127;
    int c  = tid >> 13;                     // [0, 64)

    const float* px = x   + (c * (H * W) + h * W + (w2 << 1));
    float*       po = out + ((c * 256 + 2 * h) * 256 + (w2 << 2));

#pragma unroll
    for (int b = 0; b < 8; ++b) {
        const v2f ll = *(const v2f*)(px);
        const v2f lh = *(const v2f*)(px + Q);
        const v2f hl = *(const v2f*)(px + 2 * Q);
        const v2f hh = *(const v2f*)(px + 3 * Q);

        v4f r0, r1;
        r0.x = 0.5f * (ll.x + lh.x + hl.x + hh.x);
        r0.y = 0.5f * (ll.x + lh.x - hl.x - hh.x);
        r0.z = 0.5f * (ll.y + lh.y + hl.y + hh.y);
        r0.w = 0.5f * (ll.y + lh.y - hl.y - hh.y);
        r1.x = 0.5f * (ll.x - lh.x + hl.x - hh.x);
        r1.y = 0.5f * (ll.x - lh.x - hl.x + hh.x);
        r1.z = 0.5f * (ll.y - lh.y + hl.y - hh.y);
        r1.w = 0.5f * (ll.y - lh.y - hl.y + hh.y);

        __builtin_nontemporal_store(r0, (v4f*)(po));
        __builtin_nontemporal_store(r1, (v4f*)(po + 256));

        px += BSTRIDE;
        po += BSTRIDE;
    }
}

extern "C" void kernel_launch(void* const* d_in, const int* in_sizes, int n_in,
                              void* d_out, int out_size, void* d_ws, size_t ws_size,
                              hipStream_t stream) {
    const float* x = (const float*)d_in[0];
    float* out = (float*)d_out;
    // 2048 blocks x 256 threads = 2^19 threads, each doing 8 batch iterations
    wav_unpack_kernel<<<2048, 256, 0, stream>>>(x, out);
}